// Round 1
// 89.214 us; speedup vs baseline: 1.1690x; 1.1690x over previous
//
#include <hip/hip_runtime.h>

#define BB 8
#define NN 4096
#define CC 64
#define CENTER (32*64 + 32)
#define MS 64            // m-split: blocks per batch in k_main
#define RR (NN/MS)       // 64 rows per block
#define GE 32            // padded group count (near + far + pad)
#define XPAD 68          // LDS row stride (floats); 272 B, 16B-aligned
#define CUT 64           // d2 >= CUT folded into uniform far group (w <= 9.1e-4)

// ---------------- compile-time geometry ----------------
struct Geom {
    short gid[2049];     // d2 -> group id (far -> NGN)
    short g2d2[64];      // near group id -> d2
    int ng;
};

constexpr Geom makeGeom() {
    Geom t{};
    bool occ[2049] = {};
    for (int y = 0; y < 64; ++y)
        for (int x = 0; x < 64; ++x) {
            int dy = y - 32, dx = x - 32;
            occ[dy*dy + dx*dx] = true;
        }
    int g = 0;
    for (int i = 0; i < CUT; ++i) {
        if (occ[i]) { t.gid[i] = (short)g; t.g2d2[g] = (short)i; ++g; }
        else t.gid[i] = (short)-1;
    }
    t.ng = g;
    for (int i = CUT; i <= 2048; ++i) t.gid[i] = occ[i] ? (short)g : (short)-1;
    return t;
}

constexpr int NGN = makeGeom().ng;                 // near groups (~29)
static_assert(NGN + 1 <= GE, "group padding");
static_assert(GE == 32, "decode assumes GE=32");
static_assert(MS * RR == NN, "geometry");
__constant__ Geom GEOM = makeGeom();

// ---------------- workspace layout (float offsets) ----------------
constexpr int OFF_PART = 0;                        // BB*MS*GE*CC  Y-partials
constexpr int OFF_ZP   = OFF_PART + BB*MS*GE*CC;   // BB*MS*GE     z-partials
constexpr int OFF_OG   = OFF_ZP + BB*MS*GE;        // BB*GE*CC     finalized

#define FMA4(A, E, V) do { (A).x += (E)*(V).x; (A).y += (E)*(V).y; \
                           (A).z += (E)*(V).z; (A).w += (E)*(V).w; } while(0)

// ---------------- kernel 1: fused prep + s + Y-accumulate ----------------
// grid MS*8: blockIdx = ms*8 + b (b fastest -> XCD round-robin)
// Y[g][i] = sum_r exp(w_g * s_r) * x[r][i]  -- projection deferred to k_final
__global__ __launch_bounds__(256) void k_main(
    const float* __restrict__ x,
    const float* __restrict__ wq, const float* __restrict__ bq,
    const float* __restrict__ wk, const float* __restrict__ bk,
    float* __restrict__ part, float* __restrict__ zpart)
{
    __shared__ __align__(16) float xs[RR*XPAD];    // 17.4 KB staged x rows
    __shared__ float qs[CC];
    __shared__ float us[CC];
    __shared__ __align__(16) float ss[RR];
    __shared__ float ts_s;

    const int tid = threadIdx.x;
    const int b   = blockIdx.x & 7;
    const int ms  = blockIdx.x >> 3;
    const int m0  = ms * RR;

    // ---- issue this block's x rows (coalesced float4) ----
    float4 xr[4];
    const float4* x4 = (const float4*)x + ((size_t)b*NN + m0)*16;
    #pragma unroll
    for (int k = 0; k < 4; ++k) xr[k] = x4[tid + 256*k];

    // ---- preamble stage 1: q_central[c] (wave 0; xc is wave-uniform -> s_loads) ----
    if (tid < CC) {
        const float* xc = x + ((size_t)b*NN + CENTER)*CC;
        const float* wr = wq + tid*CC;
        float a0 = bq[tid], a1 = 0.f, a2 = 0.f, a3 = 0.f;
        #pragma unroll
        for (int i = 0; i < CC; i += 4) {
            a0 += xc[i+0]*wr[i+0]; a1 += xc[i+1]*wr[i+1];
            a2 += xc[i+2]*wr[i+2]; a3 += xc[i+3]*wr[i+3];
        }
        qs[tid] = a0+a1+a2+a3;
    }
    // ---- stage x -> LDS (padded stride breaks column bank conflicts) ----
    #pragma unroll
    for (int k = 0; k < 4; ++k) {
        const int idx = tid + 256*k;
        *(float4*)&xs[(idx >> 4)*XPAD + (idx & 15)*4] = xr[k];
    }
    __syncthreads();

    // ---- preamble stage 2: u = wk^T q_c (coalesced wk columns), t = q_c . bk ----
    if (tid < CC) {
        float a0=0.f,a1=0.f,a2=0.f,a3=0.f;
        #pragma unroll
        for (int j = 0; j < CC; j += 4) {
            a0 += qs[j+0]*wk[(j+0)*CC + tid];
            a1 += qs[j+1]*wk[(j+1)*CC + tid];
            a2 += qs[j+2]*wk[(j+2)*CC + tid];
            a3 += qs[j+3]*wk[(j+3)*CC + tid];
        }
        us[tid] = a0+a1+a2+a3;
    } else if (tid == CC) {
        float a = 0.f;
        for (int j = 0; j < CC; ++j) a += qs[j]*bk[j];
        ts_s = a;
    }
    __syncthreads();

    // ---- s[r] = (x_r . u + t) * scale  (2 threads per row, shfl-pair reduce) ----
    if (tid < 2*RR) {
        const int r = tid >> 1, h = tid & 1;
        const float* xrow = &xs[r*XPAD + h*32];
        const float* uh = &us[h*32];
        float a0=0.f,a1=0.f,a2=0.f,a3=0.f;
        #pragma unroll
        for (int i = 0; i < 32; i += 4) {
            a0 += xrow[i+0]*uh[i+0]; a1 += xrow[i+1]*uh[i+1];
            a2 += xrow[i+2]*uh[i+2]; a3 += xrow[i+3]*uh[i+3];
        }
        float p = a0+a1+a2+a3;
        p += __shfl_xor(p, 1, 64);
        if (h == 0) ss[r] = (p + ts_s) * 0.125f;   // no max-sub: |w*s| < 6
    }
    __syncthreads();

    // ---- Y accumulate: thread = (g, i-octet); e computed on the fly ----
    const int g  = tid >> 3;
    const int i0 = (tid & 7) * 8;
    const float wg = (g < NGN) ? __expf(1.f - sqrtf((float)GEOM.g2d2[g])) : 0.f;
    float4 y0 = make_float4(0.f,0.f,0.f,0.f), y1 = make_float4(0.f,0.f,0.f,0.f);
    float z = 0.f;
    #pragma unroll 4
    for (int r4 = 0; r4 < RR; r4 += 4) {
        const float4 s4 = *(const float4*)&ss[r4];   // broadcast read
        float e;
        e = __expf(wg*s4.x); z += e;
        FMA4(y0, e, *(const float4*)&xs[(r4+0)*XPAD + i0]);
        FMA4(y1, e, *(const float4*)&xs[(r4+0)*XPAD + i0 + 4]);
        e = __expf(wg*s4.y); z += e;
        FMA4(y0, e, *(const float4*)&xs[(r4+1)*XPAD + i0]);
        FMA4(y1, e, *(const float4*)&xs[(r4+1)*XPAD + i0 + 4]);
        e = __expf(wg*s4.z); z += e;
        FMA4(y0, e, *(const float4*)&xs[(r4+2)*XPAD + i0]);
        FMA4(y1, e, *(const float4*)&xs[(r4+2)*XPAD + i0 + 4]);
        e = __expf(wg*s4.w); z += e;
        FMA4(y0, e, *(const float4*)&xs[(r4+3)*XPAD + i0]);
        FMA4(y1, e, *(const float4*)&xs[(r4+3)*XPAD + i0 + 4]);
    }
    // each (g,i) owned by exactly one thread -> no reduce, coalesced store
    float4* p4 = (float4*)part + ((size_t)((b*MS + ms)*GE + g)*CC + i0)/4;
    p4[0] = y0; p4[1] = y1;
    if ((tid & 7) == 0) zpart[(b*MS + ms)*GE + g] = z;
}

// ---------------- kernel 2: reduce Y + apply wv, wp, biases ----------------
// grid BB*GE = 256 blocks; block = (b,g)
__global__ __launch_bounds__(256) void k_final(
    const float* __restrict__ part, const float* __restrict__ zpart,
    const float* __restrict__ wv, const float* __restrict__ bv,
    const float* __restrict__ wp, const float* __restrict__ bp,
    float* __restrict__ og)
{
    __shared__ float yred[4*CC];
    __shared__ float ysh[CC];
    __shared__ float hsh[CC];
    __shared__ float zsh;

    const int tid = threadIdx.x;
    const int b = blockIdx.x >> 5, g = blockIdx.x & 31;
    const int i = tid & 63, q = tid >> 6;

    float a = 0.f;
    #pragma unroll
    for (int j = 0; j < MS/4; ++j) {
        const int ms = q*(MS/4) + j;
        a += part[((size_t)(b*MS + ms)*GE + g)*CC + i];
    }
    yred[q*CC + i] = a;

    float zv = 0.f;
    if (tid < 64) {                                  // wave 0: z reduce
        zv = zpart[(b*MS + tid)*GE + g];
        zv += __shfl_xor(zv, 1, 64);
        zv += __shfl_xor(zv, 2, 64);
        zv += __shfl_xor(zv, 4, 64);
        zv += __shfl_xor(zv, 8, 64);
        zv += __shfl_xor(zv, 16, 64);
        zv += __shfl_xor(zv, 32, 64);
        if (tid == 0) zsh = zv;
    }
    __syncthreads();
    if (tid < CC)
        ysh[tid] = yred[tid] + yred[CC+tid] + yred[2*CC+tid] + yred[3*CC+tid];
    __syncthreads();
    if (tid < CC) {                                  // h[j] = wv[j,:] . Y ; fold /z + bv
        const float* wr = wv + tid*CC;
        float a0=0.f,a1=0.f,a2=0.f,a3=0.f;
        #pragma unroll
        for (int j = 0; j < CC; j += 4) {
            a0 += wr[j+0]*ysh[j+0]; a1 += wr[j+1]*ysh[j+1];
            a2 += wr[j+2]*ysh[j+2]; a3 += wr[j+3]*ysh[j+3];
        }
        hsh[tid] = (a0+a1+a2+a3)/zsh + bv[tid];
    }
    __syncthreads();
    if (tid < CC) {                                  // og[c] = wp[c,:] . hh + bp
        const float* wr = wp + tid*CC;
        float a0=bp[tid],a1=0.f,a2=0.f,a3=0.f;
        #pragma unroll
        for (int j = 0; j < CC; j += 4) {
            a0 += wr[j+0]*hsh[j+0]; a1 += wr[j+1]*hsh[j+1];
            a2 += wr[j+2]*hsh[j+2]; a3 += wr[j+3]*hsh[j+3];
        }
        og[((size_t)b*GE + g)*CC + tid] = a0+a1+a2+a3;
    }
}

// ---------------- kernel 3: gather ----------------
__global__ __launch_bounds__(256) void k_out(
    const float* __restrict__ og, float* __restrict__ out)
{
    const int i4 = blockIdx.x * 256 + threadIdx.x;   // [0, BB*NN*16)
    const int c4 = i4 & 15;
    const int n  = (i4 >> 4) & (NN - 1);
    const int bb = i4 >> 16;
    const int dy = (n >> 6) - 32, dx = (n & 63) - 32;
    const int g  = GEOM.gid[dy*dy + dx*dx];
    ((float4*)out)[i4] = ((const float4*)og)[(size_t)(bb*GE + g)*16 + c4];
}

// ---------------- host ----------------
extern "C" void kernel_launch(void* const* d_in, const int* in_sizes, int n_in,
                              void* d_out, int out_size, void* d_ws, size_t ws_size,
                              hipStream_t stream) {
    const float* x  = (const float*)d_in[0];
    const float* wq = (const float*)d_in[1];
    const float* bq = (const float*)d_in[2];
    const float* wk = (const float*)d_in[3];
    const float* bk = (const float*)d_in[4];
    const float* wv = (const float*)d_in[5];
    const float* bv = (const float*)d_in[6];
    const float* wp = (const float*)d_in[7];
    const float* bp = (const float*)d_in[8];
    float* ws = (float*)d_ws;

    k_main<<<MS*8, 256, 0, stream>>>(x, wq, bq, wk, bk,
                                     ws + OFF_PART, ws + OFF_ZP);
    k_final<<<BB*GE, 256, 0, stream>>>(ws + OFF_PART, ws + OFF_ZP,
                                       wv, bv, wp, bp, ws + OFF_OG);
    k_out<<<2048, 256, 0, stream>>>(ws + OFF_OG, (float*)d_out);
}

// Round 2
// 89.173 us; speedup vs baseline: 1.1696x; 1.0005x over previous
//
#include <hip/hip_runtime.h>

#define BB 8
#define NN 4096
#define CC 64
#define CENTER (32*64 + 32)
#define MS 64            // m-split: blocks per batch in k_main
#define RR (NN/MS)       // 64 rows per block
#define GE 32            // padded group count (near + far + pad)
#define XPAD 68          // LDS x row stride (floats); 272 B, 16B-aligned
#define ESP 68           // LDS Es row stride (floats)
#define CUT 64           // d2 >= CUT folded into uniform far group (w <= 9.1e-4)
#define CHUNK 128        // output positions per finalize job

// ---------------- compile-time geometry ----------------
struct Geom {
    short gid[2049];     // d2 -> group id (far -> NGN)
    short g2d2[64];      // near group id -> d2
    int ng;
};

constexpr Geom makeGeom() {
    Geom t{};
    bool occ[2049] = {};
    for (int y = 0; y < 64; ++y)
        for (int x = 0; x < 64; ++x) {
            int dy = y - 32, dx = x - 32;
            occ[dy*dy + dx*dx] = true;
        }
    int g = 0;
    for (int i = 0; i < CUT; ++i) {
        if (occ[i]) { t.gid[i] = (short)g; t.g2d2[g] = (short)i; ++g; }
        else t.gid[i] = (short)-1;
    }
    t.ng = g;
    for (int i = CUT; i <= 2048; ++i) t.gid[i] = occ[i] ? (short)g : (short)-1;
    return t;
}

constexpr int NGN = makeGeom().ng;                 // near groups (~29)
static_assert(NGN + 1 <= GE, "group padding");
static_assert(GE == 32, "decode assumes GE=32");
static_assert(MS * RR == NN, "geometry");
__constant__ Geom GEOM = makeGeom();

// ---------------- compile-time finalize job table ----------------
struct Jobs {
    int nj;
    short jg[96];                // job -> group
    short jstart[96];            // job -> first index into pos[]
    short jlen[96];              // job -> #positions (<= CHUNK)
    unsigned short pos[NN];      // positions sorted by group
};

constexpr Jobs makeJobs() {
    Jobs J{};
    Geom gm = makeGeom();
    int cnt[NGN + 1] = {};
    for (int n = 0; n < NN; ++n) {
        int dy = (n >> 6) - 32, dx = (n & 63) - 32;
        cnt[gm.gid[dy*dy + dx*dx]]++;
    }
    int off[NGN + 2]; off[0] = 0;
    for (int g = 0; g <= NGN; ++g) off[g+1] = off[g] + cnt[g];
    int cur[NGN + 1];
    for (int g = 0; g <= NGN; ++g) cur[g] = off[g];
    for (int n = 0; n < NN; ++n) {
        int dy = (n >> 6) - 32, dx = (n & 63) - 32;
        int g = gm.gid[dy*dy + dx*dx];
        J.pos[cur[g]++] = (unsigned short)n;
    }
    int j = 0;
    for (int g = 0; g <= NGN; ++g)
        for (int s = off[g]; s < off[g+1]; s += CHUNK) {
            int L = off[g+1] - s;
            J.jg[j] = (short)g; J.jstart[j] = (short)s;
            J.jlen[j] = (short)(L < CHUNK ? L : CHUNK);
            ++j;
        }
    J.nj = j;
    return J;
}

constexpr int NJ = makeJobs().nj;
static_assert(NJ <= 96, "job table overflow");
__constant__ Jobs JOBS = makeJobs();

// ---------------- workspace layout (float offsets) ----------------
constexpr int OFF_PART = 0;                        // BB*MS*GE*CC  Y-partials
constexpr int OFF_ZP   = OFF_PART + BB*MS*GE*CC;   // BB*MS*GE     z-partials

#define FMA4(A, E, V) do { (A).x += (E)*(V).x; (A).y += (E)*(V).y; \
                           (A).z += (E)*(V).z; (A).w += (E)*(V).w; } while(0)

// ---------------- kernel 1: fused prep + s + Y-accumulate ----------------
// grid MS*8: blockIdx = ms*8 + b (b fastest -> XCD round-robin)
// Y[g][i] = sum_r exp(w_g * s_r) * x[r][i]  -- projection deferred to k_fin
__global__ __launch_bounds__(256) void k_main(
    const float* __restrict__ x,
    const float* __restrict__ wq, const float* __restrict__ bq,
    const float* __restrict__ wk, const float* __restrict__ bk,
    float* __restrict__ part, float* __restrict__ zpart)
{
    __shared__ __align__(16) float xs[RR*XPAD];    // 17.4 KB staged x rows
    __shared__ __align__(16) float Es[GE*ESP];     // 8.7 KB  exp(w_g*s_r)
    __shared__ __align__(16) float qp[4][CC];      // 4-way dot partials
    __shared__ __align__(16) float qs[CC];
    __shared__ __align__(16) float us[CC];
    __shared__ __align__(16) float ss[RR];
    __shared__ float wgs[GE];
    __shared__ float ts_s;

    const int tid = threadIdx.x;
    const int b   = blockIdx.x & 7;
    const int ms  = blockIdx.x >> 3;
    const int m0  = ms * RR;
    const int c   = tid & 63;
    const int qd  = tid >> 6;                      // quarter 0..3

    // ---- issue this block's x rows (coalesced float4) ----
    float4 xr[4];
    const float4* x4 = (const float4*)x + ((size_t)b*NN + m0)*16;
    #pragma unroll
    for (int k = 0; k < 4; ++k) xr[k] = x4[tid + 256*k];

    // ---- preamble stage 1 (4-way split): q_c[c] = bq[c] + wq[c,:] . x_center ----
    {
        const float* xc = x + ((size_t)b*NN + CENTER)*CC + qd*16;
        const float* wr = wq + c*CC + qd*16;
        float a = (qd == 0) ? bq[c] : 0.f;
        #pragma unroll
        for (int i = 0; i < 16; ++i) a += xc[i]*wr[i];
        qp[qd][c] = a;
    }
    // ---- stage x -> LDS (padded stride) ----
    #pragma unroll
    for (int k = 0; k < 4; ++k) {
        const int idx = tid + 256*k;
        *(float4*)&xs[(idx >> 4)*XPAD + (idx & 15)*4] = xr[k];
    }
    __syncthreads();                               // S1: qp1, xs ready

    if (tid < CC) qs[tid] = qp[0][tid] + qp[1][tid] + qp[2][tid] + qp[3][tid];
    if (tid < GE) wgs[tid] = (tid < NGN) ? __expf(1.f - sqrtf((float)GEOM.g2d2[tid])) : 0.f;
    __syncthreads();                               // S2: qs ready, qp free

    // ---- preamble stage 2 (4-way split): u[c] = wk[:,c] . q_c ; t = q_c . bk ----
    {
        const float* wc = wk + (qd*16)*CC + c;
        float a = 0.f;
        #pragma unroll
        for (int j = 0; j < 16; ++j) a += qs[qd*16 + j] * wc[j*CC];
        qp[qd][c] = a;
    }
    if (tid >= 64 && tid < 128) {                  // wave1: t = q_c . bk
        const int l = tid - 64;
        float p = qs[l] * bk[l];
        p += __shfl_xor(p, 1, 64);
        p += __shfl_xor(p, 2, 64);
        p += __shfl_xor(p, 4, 64);
        p += __shfl_xor(p, 8, 64);
        p += __shfl_xor(p, 16, 64);
        p += __shfl_xor(p, 32, 64);
        if (l == 0) ts_s = p;
    }
    __syncthreads();                               // S3: qp2, ts ready
    if (tid < CC) us[tid] = qp[0][tid] + qp[1][tid] + qp[2][tid] + qp[3][tid];
    __syncthreads();                               // S4: us ready

    // ---- s[r] = (x_r . u + t) * scale  (4 threads/row; no max-sub: |w*s| < 6) ----
    {
        const int r = tid >> 2, h = tid & 3;
        const float4* xp = (const float4*)&xs[r*XPAD + h*16];
        const float4* up = (const float4*)&us[h*16];
        const float4 x0 = xp[0], x1 = xp[1], x2 = xp[2], x3 = xp[3];
        const float4 u0 = up[0], u1 = up[1], u2 = up[2], u3 = up[3];
        float p = x0.x*u0.x + x0.y*u0.y + x0.z*u0.z + x0.w*u0.w
                + x1.x*u1.x + x1.y*u1.y + x1.z*u1.z + x1.w*u1.w
                + x2.x*u2.x + x2.y*u2.y + x2.z*u2.z + x2.w*u2.w
                + x3.x*u3.x + x3.y*u3.y + x3.z*u3.z + x3.w*u3.w;
        p += __shfl_xor(p, 1, 64);
        p += __shfl_xor(p, 2, 64);
        if (h == 0) ss[r] = (p + ts_s) * 0.125f;
    }
    __syncthreads();                               // S5: ss ready

    // ---- Es[g][r] = exp(w_g * s_r), computed once per (g,r) ----
    {
        const int r = c;
        const float sr = ss[r];
        #pragma unroll
        for (int gg = 0; gg < 8; ++gg) {
            const int g = qd*8 + gg;
            Es[g*ESP + r] = __expf(wgs[g] * sr);
        }
    }
    __syncthreads();                               // S6: Es ready

    // ---- z[g] = sum_r Es[g][r]  (4 lanes per g) ----
    if (tid < 128) {
        const int g = tid >> 2, rq = tid & 3;
        const float4* ep = (const float4*)&Es[g*ESP + rq*16];
        const float4 e0 = ep[0], e1 = ep[1], e2 = ep[2], e3 = ep[3];
        float z = (e0.x+e0.y+e0.z+e0.w) + (e1.x+e1.y+e1.z+e1.w)
                + (e2.x+e2.y+e2.z+e2.w) + (e3.x+e3.y+e3.z+e3.w);
        z += __shfl_xor(z, 1, 64);
        z += __shfl_xor(z, 2, 64);
        if (rq == 0) zpart[(b*MS + ms)*GE + g] = z;
    }

    // ---- Y accumulate: thread = (group-pair, i-quad) ----
    const int gp = tid >> 4;                       // 0..15 -> groups 2gp, 2gp+1
    const int i0 = (tid & 15) * 4;
    const int gA = 2*gp;
    float4 y0 = make_float4(0.f,0.f,0.f,0.f), y1 = make_float4(0.f,0.f,0.f,0.f);
    #pragma unroll 4
    for (int r4 = 0; r4 < RR; r4 += 4) {
        const float4 eA = *(const float4*)&Es[gA*ESP + r4];
        const float4 eB = *(const float4*)&Es[(gA+1)*ESP + r4];
        float4 xa;
        xa = *(const float4*)&xs[(r4+0)*XPAD + i0]; FMA4(y0, eA.x, xa); FMA4(y1, eB.x, xa);
        xa = *(const float4*)&xs[(r4+1)*XPAD + i0]; FMA4(y0, eA.y, xa); FMA4(y1, eB.y, xa);
        xa = *(const float4*)&xs[(r4+2)*XPAD + i0]; FMA4(y0, eA.z, xa); FMA4(y1, eB.z, xa);
        xa = *(const float4*)&xs[(r4+3)*XPAD + i0]; FMA4(y0, eA.w, xa); FMA4(y1, eB.w, xa);
    }
    // each (g,i) owned by exactly one thread -> no reduce, coalesced store
    float4* p4 = (float4*)part + ((size_t)((b*MS + ms)*GE + gA)*CC + i0)/4;
    p4[0]    = y0;
    p4[CC/4] = y1;
}

// ---------------- kernel 2: reduce Y + project + scatter output ----------------
// grid NJ*8: blockIdx = j*8 + b; job j = (group, position chunk)
__global__ __launch_bounds__(256) void k_fin(
    const float* __restrict__ part, const float* __restrict__ zpart,
    const float* __restrict__ wv, const float* __restrict__ bv,
    const float* __restrict__ wp, const float* __restrict__ bp,
    float* __restrict__ out)
{
    __shared__ float yred[4*CC];
    __shared__ float ysh[CC];
    __shared__ float hsh[CC];
    __shared__ __align__(16) float og_l[CC];
    __shared__ float zsh;

    const int tid = threadIdx.x;
    const int b   = blockIdx.x & 7;
    const int j   = blockIdx.x >> 3;
    const int g   = JOBS.jg[j];
    const int c   = tid & 63;
    const int q   = tid >> 6;

    // reduce Y over ms (4-way split)
    float a = 0.f;
    #pragma unroll
    for (int m = 0; m < MS/4; ++m)
        a += part[((size_t)((b*MS + q*(MS/4) + m)*GE + g))*CC + c];
    yred[q*CC + c] = a;

    if (tid < 64) {                                // wave0: z reduce
        float zv = zpart[(b*MS + tid)*GE + g];
        zv += __shfl_xor(zv, 1, 64);
        zv += __shfl_xor(zv, 2, 64);
        zv += __shfl_xor(zv, 4, 64);
        zv += __shfl_xor(zv, 8, 64);
        zv += __shfl_xor(zv, 16, 64);
        zv += __shfl_xor(zv, 32, 64);
        if (tid == 0) zsh = zv;
    }
    __syncthreads();
    if (tid < CC) ysh[tid] = yred[tid] + yred[CC+tid] + yred[2*CC+tid] + yred[3*CC+tid];
    __syncthreads();

    // h[c] = (wv[c,:] . Y)/z + bv[c]   (4-way split)
    {
        const float* wr = wv + c*CC + q*16;
        const float* yp = ysh + q*16;
        float p = 0.f;
        #pragma unroll
        for (int i = 0; i < 16; ++i) p += wr[i]*yp[i];
        yred[q*CC + c] = p;
    }
    __syncthreads();
    if (tid < CC)
        hsh[tid] = (yred[tid] + yred[CC+tid] + yred[2*CC+tid] + yred[3*CC+tid]) / zsh + bv[tid];
    __syncthreads();

    // og[c] = wp[c,:] . h + bp[c]   (4-way split)
    {
        const float* wr = wp + c*CC + q*16;
        const float* hp = hsh + q*16;
        float p = 0.f;
        #pragma unroll
        for (int i = 0; i < 16; ++i) p += wr[i]*hp[i];
        yred[q*CC + c] = p;
    }
    __syncthreads();
    if (tid < CC)
        og_l[tid] = yred[tid] + yred[CC+tid] + yred[2*CC+tid] + yred[3*CC+tid] + bp[tid];
    __syncthreads();

    // scatter: 16 positions per iteration, 16 lanes per position (256 B rows)
    const int start = JOBS.jstart[j], len = JOBS.jlen[j];
    const int c4 = tid & 15;
    const float4 val = ((const float4*)og_l)[c4];
    float4* out4 = (float4*)out + ((size_t)b << 16);
    for (int k = tid >> 4; k < len; k += 16) {
        const int n = JOBS.pos[start + k];
        out4[n*16 + c4] = val;
    }
}

// ---------------- host ----------------
extern "C" void kernel_launch(void* const* d_in, const int* in_sizes, int n_in,
                              void* d_out, int out_size, void* d_ws, size_t ws_size,
                              hipStream_t stream) {
    const float* x  = (const float*)d_in[0];
    const float* wq = (const float*)d_in[1];
    const float* bq = (const float*)d_in[2];
    const float* wk = (const float*)d_in[3];
    const float* bk = (const float*)d_in[4];
    const float* wv = (const float*)d_in[5];
    const float* bv = (const float*)d_in[6];
    const float* wp = (const float*)d_in[7];
    const float* bp = (const float*)d_in[8];
    float* ws = (float*)d_ws;

    k_main<<<MS*8, 256, 0, stream>>>(x, wq, bq, wk, bk,
                                     ws + OFF_PART, ws + OFF_ZP);
    k_fin<<<NJ*8, 256, 0, stream>>>(ws + OFF_PART, ws + OFF_ZP,
                                    wv, bv, wp, bp, (float*)d_out);
}